// Round 1
// baseline (143.353 us; speedup 1.0000x reference)
//
#include <hip/hip_runtime.h>
#include <cstddef>

namespace {
constexpr int cB = 64, cN = 34, cF = 16, cT = 96, cK = 3, cO = 64;
constexpr int NP = 36;   // padded row stride for 34x34 matrices
constexpr int HC = 80;   // H column count (5 blocks of 16)
constexpr int HP = 84;   // padded H row stride (16B-aligned rows)
constexpr float cEPS = 1e-8f;
}

// ---------------- softmax over axis=2 (i) of st_attention (B,K,N,N) ----------------
__global__ __launch_bounds__(256) void att_softmax_k(const float* __restrict__ st,
                                                     float* __restrict__ att) {
    int idx = blockIdx.x * blockDim.x + threadIdx.x;
    if (idx >= cB * cK * cN) return;
    int j = idx % cN;
    int bk = idx / cN;
    const float* base = st + (size_t)bk * cN * cN + j;
    float v[cN];
    float m = -3.402823466e38f;
#pragma unroll
    for (int i = 0; i < cN; ++i) { v[i] = base[(size_t)i * cN]; m = fmaxf(m, v[i]); }
    float s = 0.f;
#pragma unroll
    for (int i = 0; i < cN; ++i) { v[i] = __expf(v[i] - m); s += v[i]; }
    float inv = 1.f / s;
    float* ob = att + (size_t)bk * cN * cN + j;
#pragma unroll
    for (int i = 0; i < cN; ++i) ob[(size_t)i * cN] = v[i] * inv;
}

// ---------------- main: one block per (b,t) ----------------
__global__ __launch_bounds__(256, 4) void cheb_main_k(
    const float* __restrict__ x,      // (B,N,F,T)
    const float* __restrict__ att,    // (B,K,N,N) softmaxed
    const float* __restrict__ pos,    // (N,2)
    const float* __restrict__ dist,   // (N,N)
    const float* __restrict__ Th,     // (K,F,O)
    const float* __restrict__ ThL,    // (K,F,O)
    float* __restrict__ out)          // (B,N,O,T)
{
    __shared__ float s_gs[cN][cF];
    __shared__ float s_posv[cN][2];
    __shared__ float s_vn[cN], s_pn[cN], s_d0[cN], s_di1[cN], s_di2[cN];
    __shared__ float s_M1[cN][NP];  // L1  -> scaled by att1
    __shared__ float s_M2[cN][NP];  // A, then C1=2L1^2-I -> scaled by att2
    __shared__ float s_M3[cN][NP];  // L2  -> scaled by att1
    __shared__ float s_M4[cN][NP];  // C2=2L2^2-I -> scaled by att2
    __shared__ float s_H[cN][HP];   // concat H (34 x 80)

    auto& s_A = s_M2;  // adjacency lives in M2 until C1 overwrites it

    const int tid = threadIdx.x;
    // XCD swizzle: consecutive logical (b,t) cluster on one XCD for L2 locality
    const unsigned g = blockIdx.x;
    const unsigned lin = (g & 7u) * (cB * cT / 8) + (g >> 3);
    const int b = lin / cT, t = lin % cT;

    // ---- stage gs = x[b,:,:,t] and position ----
    for (int idx = tid; idx < cN * cF; idx += 256) {
        int n = idx >> 4, f = idx & 15;
        s_gs[n][f] = x[(((size_t)b * cN + n) * cF + f) * cT + t];
    }
    if (tid < cN * 2) ((float*)s_posv)[tid] = pos[tid];
    __syncthreads();

    // ---- vn, pn, att0 diagonal ----
    if (tid < cN) {
        float a = s_gs[tid][1], c2 = s_gs[tid][2];
        s_vn[tid] = sqrtf(a * a + c2 * c2);
    } else if (tid >= 64 && tid < 64 + cN) {
        int m = tid - 64;
        float a = s_posv[m][0], c2 = s_posv[m][1];
        s_pn[m] = sqrtf(a * a + c2 * c2);
    } else if (tid >= 128 && tid < 128 + cN) {
        int j = tid - 128;
        s_d0[j] = att[((size_t)b * cK) * cN * cN + j * cN + j];
    }
    __syncthreads();

    // ---- adjacency A (Frobenius normalization skipped: L is scale-invariant) ----
    for (int idx = tid; idx < cN * cN; idx += 256) {
        int i = idx / cN, m = idx - i * cN;
        float vn = s_vn[i];
        float dotv = s_gs[i][1] * s_posv[m][0] + s_gs[i][2] * s_posv[m][1];
        float cosv = dotv / (fmaxf(vn, cEPS) * fmaxf(s_pn[m], cEPS));
        cosv = fmaxf(cosv, 0.f);
        s_A[i][m] = cosv * vn / dist[i * cN + m];
    }
    __syncthreads();

    // ---- degree row/col sums -> dinv ----
    if (tid < cN) {
        float s = 0.f;
#pragma unroll
        for (int m = 0; m < cN; ++m) s += s_A[tid][m];
        s_di1[tid] = (s > 0.f) ? rsqrtf(fmaxf(s, 1e-12f)) : 0.f;
    } else if (tid >= 64 && tid < 64 + cN) {
        int j = tid - 64;
        float s = 0.f;
#pragma unroll
        for (int i = 0; i < cN; ++i) s += s_A[i][j];
        s_di2[j] = (s > 0.f) ? rsqrtf(fmaxf(s, 1e-12f)) : 0.f;
    }
    __syncthreads();

    // ---- L1 = I - d1 A d1 ; L2 = I - d2 A^T d2 ----
    for (int idx = tid; idx < cN * cN; idx += 256) {
        int i = idx / cN, j = idx - i * cN;
        float a = s_A[i][j], at = s_A[j][i];
        float diag = (i == j) ? 1.f : 0.f;
        s_M1[i][j] = diag - s_di1[i] * a * s_di1[j];
        s_M3[i][j] = diag - s_di2[i] * at * s_di2[j];
    }
    __syncthreads();

    // ---- C1 = 2 L1@L1 - I (into M2, A is dead) ; C2 = 2 L2@L2 - I ----
    for (int idx = tid; idx < cN * 9; idx += 256) {
        int i = idx / 9, j4 = idx - i * 9;
        int j0 = j4 * 4;
        float4 a1 = make_float4(0.f, 0.f, 0.f, 0.f);
        float4 a2 = make_float4(0.f, 0.f, 0.f, 0.f);
        for (int q = 0; q < cN; ++q) {
            float l1 = s_M1[i][q];
            float4 r1 = *(const float4*)&s_M1[q][j0];
            a1.x = fmaf(l1, r1.x, a1.x); a1.y = fmaf(l1, r1.y, a1.y);
            a1.z = fmaf(l1, r1.z, a1.z); a1.w = fmaf(l1, r1.w, a1.w);
            float l2 = s_M3[i][q];
            float4 r2 = *(const float4*)&s_M3[q][j0];
            a2.x = fmaf(l2, r2.x, a2.x); a2.y = fmaf(l2, r2.y, a2.y);
            a2.z = fmaf(l2, r2.z, a2.z); a2.w = fmaf(l2, r2.w, a2.w);
        }
        float4 o1, o2;
        o1.x = 2.f * a1.x - ((i == j0 + 0) ? 1.f : 0.f);
        o1.y = 2.f * a1.y - ((i == j0 + 1) ? 1.f : 0.f);
        o1.z = 2.f * a1.z - ((i == j0 + 2) ? 1.f : 0.f);
        o1.w = 2.f * a1.w - ((i == j0 + 3) ? 1.f : 0.f);
        o2.x = 2.f * a2.x - ((i == j0 + 0) ? 1.f : 0.f);
        o2.y = 2.f * a2.y - ((i == j0 + 1) ? 1.f : 0.f);
        o2.z = 2.f * a2.z - ((i == j0 + 2) ? 1.f : 0.f);
        o2.w = 2.f * a2.w - ((i == j0 + 3) ? 1.f : 0.f);
        *(float4*)&s_M2[i][j0] = o1;
        *(float4*)&s_M4[i][j0] = o2;
    }
    __syncthreads();

    // ---- scale cheb matrices by attention in place ----
    const float* att1 = att + ((size_t)b * cK + 1) * cN * cN;
    const float* att2 = att + ((size_t)b * cK + 2) * cN * cN;
    for (int idx = tid; idx < cN * cN; idx += 256) {
        int i = idx / cN, j = idx - i * cN;
        float a1 = att1[idx], a2 = att2[idx];
        s_M1[i][j] *= a1;
        s_M3[i][j] *= a1;
        s_M2[i][j] *= a2;
        s_M4[i][j] *= a2;
    }
    __syncthreads();

    // ---- Theta columns into registers (5 blocks x 16, column o per thread) ----
    const int o = tid & 63;
    float th[HC];
#pragma unroll
    for (int f = 0; f < cF; ++f) {
        th[f]      = Th[f * cO + o] + ThL[f * cO + o];      // k=0 merged
        th[16 + f] = Th[(cF + f) * cO + o];                 // k=1
        th[32 + f] = Th[(2 * cF + f) * cO + o];             // k=2
        th[48 + f] = ThL[(cF + f) * cO + o];                // k=1 (L branch)
        th[64 + f] = ThL[(2 * cF + f) * cO + o];            // k=2 (L branch)
    }

    // ---- H[j][p*16+f] : p0 diag term, p1..p4 = M^T @ gs ----
    for (int idx = tid; idx < cN * 20; idx += 256) {
        int j = idx / 20, c4 = idx - j * 20;
        int p = c4 >> 2, f0 = (c4 & 3) << 2;
        float4 r;
        if (p == 0) {
            float d = s_d0[j];
            float4 gv = *(const float4*)&s_gs[j][f0];
            r = make_float4(d * gv.x, d * gv.y, d * gv.z, d * gv.w);
        } else {
            const float (*M)[NP] = (p == 1) ? s_M1 : (p == 2) ? s_M2
                                 : (p == 3) ? s_M3 : s_M4;
            float4 acc = make_float4(0.f, 0.f, 0.f, 0.f);
            for (int i2 = 0; i2 < cN; ++i2) {
                float mm = M[i2][j];
                float4 gv = *(const float4*)&s_gs[i2][f0];
                acc.x = fmaf(mm, gv.x, acc.x); acc.y = fmaf(mm, gv.y, acc.y);
                acc.z = fmaf(mm, gv.z, acc.z); acc.w = fmaf(mm, gv.w, acc.w);
            }
            r = acc;
        }
        *(float4*)&s_H[j][(p << 4) + f0] = r;
    }
    __syncthreads();

    // ---- final: out[j,o] = relu( H[j,:] . th ) ----
    const int jb = tid >> 6;
    for (int j = jb; j < cN; j += 4) {
        float acc = 0.f;
#pragma unroll
        for (int c = 0; c < HC; ++c) acc = fmaf(s_H[j][c], th[c], acc);
        out[(((size_t)b * cN + j) * cO + o) * cT + t] = fmaxf(acc, 0.f);
    }
}

extern "C" void kernel_launch(void* const* d_in, const int* in_sizes, int n_in,
                              void* d_out, int out_size, void* d_ws, size_t ws_size,
                              hipStream_t stream) {
    const float* x    = (const float*)d_in[0];
    const float* st   = (const float*)d_in[1];
    const float* pos  = (const float*)d_in[2];
    const float* dist = (const float*)d_in[3];
    const float* Th   = (const float*)d_in[4];
    const float* ThL  = (const float*)d_in[5];
    float* out = (float*)d_out;
    float* att = (float*)d_ws;  // B*K*N*N floats = 888 KB

    att_softmax_k<<<(cB * cK * cN + 255) / 256, 256, 0, stream>>>(st, att);
    cheb_main_k<<<cB * cT, 256, 0, stream>>>(x, att, pos, dist, Th, ThL, out);
}